// Round 1
// baseline (978.371 us; speedup 1.0000x reference)
//
#include <hip/hip_runtime.h>
#include <hip/hip_bf16.h>

#define N_NODES 50000
#define N_EDGES 1600000
#define HIDDEN  128
#define EPS_C   0.3f

// ---------------- degree (over row) + col histogram ----------------
__global__ void k_count(const int* __restrict__ ei, int* __restrict__ deg, int* __restrict__ cnt) {
    int e = blockIdx.x * blockDim.x + threadIdx.x;
    if (e >= N_EDGES) return;
    int r = ei[e];             // row
    int c = ei[N_EDGES + e];   // col
    atomicAdd(&deg[r], 1);
    atomicAdd(&cnt[c], 1);
}

__global__ void k_nd(const int* __restrict__ deg, float* __restrict__ nd) {
    int i = blockIdx.x * blockDim.x + threadIdx.x;
    if (i >= N_NODES) return;
    nd[i] = rsqrtf(fmaxf((float)deg[i], 1.0f));
}

// ---------------- 3-kernel exclusive scan of cnt -> colptr ----------------
__global__ __launch_bounds__(256) void k_scan_a(const int* __restrict__ cnt,
                                                int* __restrict__ out, int* __restrict__ partials) {
    __shared__ int sh[256];
    int t = threadIdx.x;
    int base = blockIdx.x * 1024 + t * 4;
    int v0 = (base + 0 < N_NODES) ? cnt[base + 0] : 0;
    int v1 = (base + 1 < N_NODES) ? cnt[base + 1] : 0;
    int v2 = (base + 2 < N_NODES) ? cnt[base + 2] : 0;
    int v3 = (base + 3 < N_NODES) ? cnt[base + 3] : 0;
    int s = v0 + v1 + v2 + v3;
    sh[t] = s;
    __syncthreads();
    for (int off = 1; off < 256; off <<= 1) {
        int add = (t >= off) ? sh[t - off] : 0;
        __syncthreads();
        sh[t] += add;
        __syncthreads();
    }
    int excl = sh[t] - s;   // exclusive prefix of thread sums
    if (t == 255) partials[blockIdx.x] = sh[255];
    if (base + 0 < N_NODES) out[base + 0] = excl;
    if (base + 1 < N_NODES) out[base + 1] = excl + v0;
    if (base + 2 < N_NODES) out[base + 2] = excl + v0 + v1;
    if (base + 3 < N_NODES) out[base + 3] = excl + v0 + v1 + v2;
}

__global__ void k_scan_b(int* partials, int* colptr, int nb) {
    if (threadIdx.x == 0 && blockIdx.x == 0) {
        int run = 0;
        for (int i = 0; i < nb; ++i) { int t = partials[i]; partials[i] = run; run += t; }
        colptr[N_NODES] = run;   // == E
    }
}

__global__ void k_scan_c(int* __restrict__ colptr, const int* __restrict__ partials) {
    int i = blockIdx.x * blockDim.x + threadIdx.x;
    if (i >= N_NODES) return;
    colptr[i] += partials[i >> 10];
}

// ---------------- scatter edges into CSR (by col), coef = nd[r]*nd[c] ----------------
__global__ void k_scatter(const int* __restrict__ ei, const int* __restrict__ colptr,
                          int* __restrict__ fill, const float* __restrict__ nd,
                          int2* __restrict__ csr) {
    int e = blockIdx.x * blockDim.x + threadIdx.x;
    if (e >= N_EDGES) return;
    int r = ei[e];
    int c = ei[N_EDGES + e];
    int pos = colptr[c] + atomicAdd(&fill[c], 1);
    int2 v;
    v.x = r;
    v.y = __float_as_int(nd[r] * nd[c]);
    csr[pos] = v;
}

// ---------------- GEMM1: h = relu(x @ W1^T + b1), 50000x512 * (128x512)^T ----------------
// tile M=64, N=128 (all), K-tile=32; 256 threads; micro-tile 4x8 per thread
__global__ __launch_bounds__(256) void k_gemm1(const float* __restrict__ x, const float* __restrict__ w,
                                               const float* __restrict__ bias, float* __restrict__ h) {
    __shared__ float xs[32][68];    // [k][m], stride 68 (272B, 16B-aligned)
    __shared__ float ws[32][132];   // [k][n], stride 132 (528B, 16B-aligned)
    int tid = threadIdx.x;
    int m0 = blockIdx.x * 64;
    int tx = tid & 15;    // col group: n = tx*8 .. +7
    int ty = tid >> 4;    // row group: m = ty*4 .. +3
    float acc[4][8];
#pragma unroll
    for (int i = 0; i < 4; ++i)
#pragma unroll
        for (int j = 0; j < 8; ++j) acc[i][j] = 0.f;

    for (int k0 = 0; k0 < 512; k0 += 32) {
        // stage x tile: 64 rows x 32 k = 512 float4, 2 per thread
#pragma unroll
        for (int it = 0; it < 2; ++it) {
            int idx = tid + it * 256;   // 0..511
            int row = idx >> 3;
            int kq  = idx & 7;
            int gm = m0 + row;
            float4 val = make_float4(0.f, 0.f, 0.f, 0.f);
            if (gm < N_NODES) val = *(const float4*)&x[(size_t)gm * 512 + k0 + kq * 4];
            xs[kq * 4 + 0][row] = val.x;
            xs[kq * 4 + 1][row] = val.y;
            xs[kq * 4 + 2][row] = val.z;
            xs[kq * 4 + 3][row] = val.w;
        }
        // stage w tile: 128 n x 32 k = 1024 float4, 4 per thread
#pragma unroll
        for (int it = 0; it < 4; ++it) {
            int idx = tid + it * 256;   // 0..1023
            int n  = idx >> 3;
            int kq = idx & 7;
            float4 val = *(const float4*)&w[(size_t)n * 512 + k0 + kq * 4];
            ws[kq * 4 + 0][n] = val.x;
            ws[kq * 4 + 1][n] = val.y;
            ws[kq * 4 + 2][n] = val.z;
            ws[kq * 4 + 3][n] = val.w;
        }
        __syncthreads();
#pragma unroll
        for (int k = 0; k < 32; ++k) {
            float4 a  = *(const float4*)&xs[k][ty * 4];
            float4 b0 = *(const float4*)&ws[k][tx * 8];
            float4 b1 = *(const float4*)&ws[k][tx * 8 + 4];
            float av[4] = {a.x, a.y, a.z, a.w};
            float bv[8] = {b0.x, b0.y, b0.z, b0.w, b1.x, b1.y, b1.z, b1.w};
#pragma unroll
            for (int i = 0; i < 4; ++i)
#pragma unroll
                for (int j = 0; j < 8; ++j)
                    acc[i][j] = fmaf(av[i], bv[j], acc[i][j]);
        }
        __syncthreads();
    }
    // epilogue: bias + relu, vectorized stores
    float b0v[8];
#pragma unroll
    for (int j = 0; j < 8; ++j) b0v[j] = bias[tx * 8 + j];
#pragma unroll
    for (int i = 0; i < 4; ++i) {
        int gm = m0 + ty * 4 + i;
        if (gm >= N_NODES) continue;
        float4 o0, o1;
        o0.x = fmaxf(acc[i][0] + b0v[0], 0.f);
        o0.y = fmaxf(acc[i][1] + b0v[1], 0.f);
        o0.z = fmaxf(acc[i][2] + b0v[2], 0.f);
        o0.w = fmaxf(acc[i][3] + b0v[3], 0.f);
        o1.x = fmaxf(acc[i][4] + b0v[4], 0.f);
        o1.y = fmaxf(acc[i][5] + b0v[5], 0.f);
        o1.z = fmaxf(acc[i][6] + b0v[6], 0.f);
        o1.w = fmaxf(acc[i][7] + b0v[7], 0.f);
        *(float4*)&h[(size_t)gm * HIDDEN + tx * 8]     = o0;
        *(float4*)&h[(size_t)gm * HIDDEN + tx * 8 + 4] = o1;
    }
}

// ---------------- propagation layer: one wave per node over CSR ----------------
__global__ __launch_bounds__(256) void k_prop(const float* __restrict__ h, const float* __restrict__ raw,
                                              const int* __restrict__ colptr, const int2* __restrict__ csr,
                                              const float* __restrict__ gw, const float* __restrict__ gb,
                                              int layer, float* __restrict__ hn) {
    int node = blockIdx.x * 4 + (threadIdx.x >> 6);
    int lane = threadIdx.x & 63;
    if (node >= N_NODES) return;
    const float2* hv = (const float2*)h;
    float wr0 = gw[layer * 256 + 2 * lane];
    float wr1 = gw[layer * 256 + 2 * lane + 1];
    float wc0 = gw[layer * 256 + 128 + 2 * lane];
    float wc1 = gw[layer * 256 + 128 + 2 * lane + 1];
    float2 hc = hv[(size_t)node * 64 + lane];
    float dotc = hc.x * wc0 + hc.y * wc1;
#pragma unroll
    for (int off = 32; off >= 1; off >>= 1) dotc += __shfl_xor(dotc, off, 64);
    dotc += gb[layer];

    float acc0 = 0.f, acc1 = 0.f;
    int beg = colptr[node], end = colptr[node + 1];
    for (int e = beg; e < end; ++e) {
        int2 ent = csr[e];
        int r = ent.x;
        float cf = __int_as_float(ent.y);
        float2 hr = hv[(size_t)r * 64 + lane];
        float d = hr.x * wr0 + hr.y * wr1;
#pragma unroll
        for (int off = 32; off >= 1; off >>= 1) d += __shfl_xor(d, off, 64);
        float g = tanhf(d + dotc);
        float wgt = g * cf;
        acc0 = fmaf(wgt, hr.x, acc0);
        acc1 = fmaf(wgt, hr.y, acc1);
    }
    float2 rw = ((const float2*)raw)[(size_t)node * 64 + lane];
    float2 o;
    o.x = fmaf(EPS_C, rw.x, acc0);
    o.y = fmaf(EPS_C, rw.y, acc1);
    ((float2*)hn)[(size_t)node * 64 + lane] = o;
}

// ---------------- output: logits = h @ W2^T + b2, then log_softmax ----------------
__global__ __launch_bounds__(256) void k_out(const float* __restrict__ h, const float* __restrict__ w2,
                                             const float* __restrict__ b2, float* __restrict__ out) {
    __shared__ float w2t[128][40];   // transposed: w2t[i][j] = w2[j][i]
    __shared__ float hs[4][128];
    int wid  = threadIdx.x >> 6;
    int lane = threadIdx.x & 63;
    int node = blockIdx.x * 4 + wid;

    for (int idx = threadIdx.x; idx < 40 * 128; idx += 256) {
        int j = idx >> 7;
        int i = idx & 127;
        w2t[i][j] = w2[idx];
    }
    if (node < N_NODES) {
        const float2* hvv = (const float2*)h;
        float2 v = hvv[(size_t)node * 64 + lane];
        hs[wid][2 * lane]     = v.x;
        hs[wid][2 * lane + 1] = v.y;
    }
    __syncthreads();
    if (node < N_NODES) {
        int j = lane;
        float logit = -INFINITY;
        if (j < 40) {
            float a = 0.f;
#pragma unroll 8
            for (int i = 0; i < 128; ++i) a = fmaf(hs[wid][i], w2t[i][j], a);
            logit = a + b2[j];
        }
        float mx = logit;
#pragma unroll
        for (int off = 32; off >= 1; off >>= 1) mx = fmaxf(mx, __shfl_xor(mx, off, 64));
        float ex = (j < 40) ? expf(logit - mx) : 0.f;
        float sum = ex;
#pragma unroll
        for (int off = 32; off >= 1; off >>= 1) sum += __shfl_xor(sum, off, 64);
        float ls = logf(sum);
        if (j < 40) out[(size_t)node * 40 + j] = logit - mx - ls;
    }
}

extern "C" void kernel_launch(void* const* d_in, const int* in_sizes, int n_in,
                              void* d_out, int out_size, void* d_ws, size_t ws_size,
                              hipStream_t stream) {
    const float* x   = (const float*)d_in[0];
    const int*   ei  = (const int*)  d_in[1];
    const float* t1w = (const float*)d_in[2];
    const float* t1b = (const float*)d_in[3];
    const float* gw  = (const float*)d_in[4];
    const float* gb  = (const float*)d_in[5];
    const float* w2  = (const float*)d_in[6];
    const float* b2  = (const float*)d_in[7];
    float* out = (float*)d_out;

    char* p = (char*)d_ws;
    int*   deg      = (int*)p;   p += (size_t)N_NODES * 4;
    int*   cnt      = (int*)p;   p += (size_t)N_NODES * 4;
    int*   fill     = (int*)p;   p += (size_t)N_NODES * 4;
    int*   colptr   = (int*)p;   p += (size_t)(N_NODES + 64) * 4;
    int*   partials = (int*)p;   p += 256 * 4;
    float* nd       = (float*)p; p += (size_t)N_NODES * 4;
    int2*  csr      = (int2*)p;  p += (size_t)N_EDGES * 8;
    float* h0       = (float*)p; p += (size_t)N_NODES * HIDDEN * 4;
    float* h1       = (float*)p; p += (size_t)N_NODES * HIDDEN * 4;
    float* h2       = (float*)p; p += (size_t)N_NODES * HIDDEN * 4;

    // zero the three atomic-counter arrays (contiguous)
    hipMemsetAsync(deg, 0, (size_t)N_NODES * 3 * 4, stream);

    k_count<<<(N_EDGES + 255) / 256, 256, 0, stream>>>(ei, deg, cnt);
    k_nd<<<(N_NODES + 255) / 256, 256, 0, stream>>>(deg, nd);
    int nb = (N_NODES + 1023) / 1024;   // 49
    k_scan_a<<<nb, 256, 0, stream>>>(cnt, colptr, partials);
    k_scan_b<<<1, 64, 0, stream>>>(partials, colptr, nb);
    k_scan_c<<<(N_NODES + 255) / 256, 256, 0, stream>>>(colptr, partials);
    k_scatter<<<(N_EDGES + 255) / 256, 256, 0, stream>>>(ei, colptr, fill, nd, csr);
    k_gemm1<<<(N_NODES + 63) / 64, 256, 0, stream>>>(x, t1w, t1b, h0);
    k_prop<<<(N_NODES + 3) / 4, 256, 0, stream>>>(h0, h0, colptr, csr, gw, gb, 0, h1);
    k_prop<<<(N_NODES + 3) / 4, 256, 0, stream>>>(h1, h0, colptr, csr, gw, gb, 1, h2);
    k_out<<<(N_NODES + 3) / 4, 256, 0, stream>>>(h2, w2, b2, out);
}

// Round 2
// 843.412 us; speedup vs baseline: 1.1600x; 1.1600x over previous
//
#include <hip/hip_runtime.h>
#include <hip/hip_bf16.h>

#define N_NODES 50000
#define N_EDGES 1600000
#define HIDDEN  128
#define EPS_C   0.3f

// ---------------- degree (over row) + col histogram ----------------
__global__ void k_count(const int* __restrict__ ei, int* __restrict__ deg, int* __restrict__ cnt) {
    int e = blockIdx.x * blockDim.x + threadIdx.x;
    if (e >= N_EDGES) return;
    int r = ei[e];             // row
    int c = ei[N_EDGES + e];   // col
    atomicAdd(&deg[r], 1);
    atomicAdd(&cnt[c], 1);
}

__global__ void k_nd(const int* __restrict__ deg, float* __restrict__ nd) {
    int i = blockIdx.x * blockDim.x + threadIdx.x;
    if (i >= N_NODES) return;
    nd[i] = rsqrtf(fmaxf((float)deg[i], 1.0f));
}

// ---------------- 3-kernel exclusive scan of cnt -> colptr ----------------
__global__ __launch_bounds__(256) void k_scan_a(const int* __restrict__ cnt,
                                                int* __restrict__ out, int* __restrict__ partials) {
    __shared__ int sh[256];
    int t = threadIdx.x;
    int base = blockIdx.x * 1024 + t * 4;
    int v0 = (base + 0 < N_NODES) ? cnt[base + 0] : 0;
    int v1 = (base + 1 < N_NODES) ? cnt[base + 1] : 0;
    int v2 = (base + 2 < N_NODES) ? cnt[base + 2] : 0;
    int v3 = (base + 3 < N_NODES) ? cnt[base + 3] : 0;
    int s = v0 + v1 + v2 + v3;
    sh[t] = s;
    __syncthreads();
    for (int off = 1; off < 256; off <<= 1) {
        int add = (t >= off) ? sh[t - off] : 0;
        __syncthreads();
        sh[t] += add;
        __syncthreads();
    }
    int excl = sh[t] - s;
    if (t == 255) partials[blockIdx.x] = sh[255];
    if (base + 0 < N_NODES) out[base + 0] = excl;
    if (base + 1 < N_NODES) out[base + 1] = excl + v0;
    if (base + 2 < N_NODES) out[base + 2] = excl + v0 + v1;
    if (base + 3 < N_NODES) out[base + 3] = excl + v0 + v1 + v2;
}

__global__ void k_scan_b(int* partials, int* colptr, int nb) {
    if (threadIdx.x == 0 && blockIdx.x == 0) {
        int run = 0;
        for (int i = 0; i < nb; ++i) { int t = partials[i]; partials[i] = run; run += t; }
        colptr[N_NODES] = run;   // == E
    }
}

__global__ void k_scan_c(int* __restrict__ colptr, const int* __restrict__ partials) {
    int i = blockIdx.x * blockDim.x + threadIdx.x;
    if (i >= N_NODES) return;
    colptr[i] += partials[i >> 10];
}

// ---------------- scatter edges into CSR (by col), coef = nd[r]*nd[c] ----------------
__global__ void k_scatter(const int* __restrict__ ei, const int* __restrict__ colptr,
                          int* __restrict__ fill, const float* __restrict__ nd,
                          int2* __restrict__ csr) {
    int e = blockIdx.x * blockDim.x + threadIdx.x;
    if (e >= N_EDGES) return;
    int r = ei[e];
    int c = ei[N_EDGES + e];
    int pos = colptr[c] + atomicAdd(&fill[c], 1);
    int2 v;
    v.x = r;
    v.y = __float_as_int(nd[r] * nd[c]);
    csr[pos] = v;
}

// ---------------- GEMM1: h = relu(x @ W1^T + b1) ----------------
__global__ __launch_bounds__(256) void k_gemm1(const float* __restrict__ x, const float* __restrict__ w,
                                               const float* __restrict__ bias, float* __restrict__ h) {
    __shared__ float xs[32][68];
    __shared__ float ws[32][132];
    int tid = threadIdx.x;
    int m0 = blockIdx.x * 64;
    int tx = tid & 15;
    int ty = tid >> 4;
    float acc[4][8];
#pragma unroll
    for (int i = 0; i < 4; ++i)
#pragma unroll
        for (int j = 0; j < 8; ++j) acc[i][j] = 0.f;

    for (int k0 = 0; k0 < 512; k0 += 32) {
#pragma unroll
        for (int it = 0; it < 2; ++it) {
            int idx = tid + it * 256;
            int row = idx >> 3;
            int kq  = idx & 7;
            int gm = m0 + row;
            float4 val = make_float4(0.f, 0.f, 0.f, 0.f);
            if (gm < N_NODES) val = *(const float4*)&x[(size_t)gm * 512 + k0 + kq * 4];
            xs[kq * 4 + 0][row] = val.x;
            xs[kq * 4 + 1][row] = val.y;
            xs[kq * 4 + 2][row] = val.z;
            xs[kq * 4 + 3][row] = val.w;
        }
#pragma unroll
        for (int it = 0; it < 4; ++it) {
            int idx = tid + it * 256;
            int n  = idx >> 3;
            int kq = idx & 7;
            float4 val = *(const float4*)&w[(size_t)n * 512 + k0 + kq * 4];
            ws[kq * 4 + 0][n] = val.x;
            ws[kq * 4 + 1][n] = val.y;
            ws[kq * 4 + 2][n] = val.z;
            ws[kq * 4 + 3][n] = val.w;
        }
        __syncthreads();
#pragma unroll
        for (int k = 0; k < 32; ++k) {
            float4 a  = *(const float4*)&xs[k][ty * 4];
            float4 b0 = *(const float4*)&ws[k][tx * 8];
            float4 b1 = *(const float4*)&ws[k][tx * 8 + 4];
            float av[4] = {a.x, a.y, a.z, a.w};
            float bv[8] = {b0.x, b0.y, b0.z, b0.w, b1.x, b1.y, b1.z, b1.w};
#pragma unroll
            for (int i = 0; i < 4; ++i)
#pragma unroll
                for (int j = 0; j < 8; ++j)
                    acc[i][j] = fmaf(av[i], bv[j], acc[i][j]);
        }
        __syncthreads();
    }
    float b0v[8];
#pragma unroll
    for (int j = 0; j < 8; ++j) b0v[j] = bias[tx * 8 + j];
#pragma unroll
    for (int i = 0; i < 4; ++i) {
        int gm = m0 + ty * 4 + i;
        if (gm >= N_NODES) continue;
        float4 o0, o1;
        o0.x = fmaxf(acc[i][0] + b0v[0], 0.f);
        o0.y = fmaxf(acc[i][1] + b0v[1], 0.f);
        o0.z = fmaxf(acc[i][2] + b0v[2], 0.f);
        o0.w = fmaxf(acc[i][3] + b0v[3], 0.f);
        o1.x = fmaxf(acc[i][4] + b0v[4], 0.f);
        o1.y = fmaxf(acc[i][5] + b0v[5], 0.f);
        o1.z = fmaxf(acc[i][6] + b0v[6], 0.f);
        o1.w = fmaxf(acc[i][7] + b0v[7], 0.f);
        *(float4*)&h[(size_t)gm * HIDDEN + tx * 8]     = o0;
        *(float4*)&h[(size_t)gm * HIDDEN + tx * 8 + 4] = o1;
    }
}

// ---------------- per-node gate dot products: dr = h.w_r, dcb = h.w_c + gb ----------------
__global__ __launch_bounds__(256) void k_dot(const float* __restrict__ h, const float* __restrict__ gw,
                                             const float* __restrict__ gb, int layer,
                                             float* __restrict__ dr, float* __restrict__ dcb) {
    int node = blockIdx.x * 4 + (threadIdx.x >> 6);
    int lane = threadIdx.x & 63;
    if (node >= N_NODES) return;
    const float2* hv = (const float2*)h;
    float2 wr = ((const float2*)(gw + layer * 256))[lane];
    float2 wc = ((const float2*)(gw + layer * 256 + 128))[lane];
    float2 hc = hv[(size_t)node * 64 + lane];
    float a = hc.x * wr.x + hc.y * wr.y;
    float b = hc.x * wc.x + hc.y * wc.y;
#pragma unroll
    for (int off = 32; off >= 1; off >>= 1) {
        a += __shfl_xor(a, off, 64);
        b += __shfl_xor(b, off, 64);
    }
    if (lane == 0) {
        dr[node]  = a;
        dcb[node] = b + gb[layer];
    }
}

// ---------------- per-edge gate weight: w = tanh(dr[row]+dcb[col]) * coef ----------------
__global__ __launch_bounds__(256) void k_gate(const int* __restrict__ colptr, const int2* __restrict__ csr,
                                              const float* __restrict__ dr, const float* __restrict__ dcb,
                                              float* __restrict__ wbuf) {
    int node = blockIdx.x * 4 + (threadIdx.x >> 6);
    int lane = threadIdx.x & 63;
    if (node >= N_NODES) return;
    int beg = colptr[node], end = colptr[node + 1];
    float dc = dcb[node];
    for (int e = beg + lane; e < end; e += 64) {
        int2 ent = csr[e];
        float xx = dr[ent.x] + dc;
        float t = __expf(2.0f * xx);          // saturates to inf / 0, no NaN below
        float g = 1.0f - 2.0f / (t + 1.0f);   // == tanh(xx)
        wbuf[e] = g * __int_as_float(ent.y);
    }
}

// ---------------- propagation: pure weighted gather, wave per node ----------------
__global__ __launch_bounds__(256) void k_prop(const float* __restrict__ h, const float* __restrict__ raw,
                                              const int* __restrict__ colptr, const int2* __restrict__ csr,
                                              const float* __restrict__ wbuf, float* __restrict__ hn) {
    int node = blockIdx.x * 4 + (threadIdx.x >> 6);
    int lane = threadIdx.x & 63;
    if (node >= N_NODES) return;
    const float2* hv = (const float2*)h;
    float acc0 = 0.f, acc1 = 0.f;
    int beg = colptr[node], end = colptr[node + 1];
    for (int base = beg; base < end; base += 64) {
        int e = base + lane;
        int  rr = 0;
        float wv = 0.f;
        if (e < end) {
            rr = csr[e].x;
            wv = wbuf[e];
        }
        int m = end - base; if (m > 64) m = 64;
#pragma unroll 4
        for (int j = 0; j < m; ++j) {
            int   r = __shfl(rr, j, 64);
            float w = __shfl(wv, j, 64);
            float2 hr = hv[(size_t)r * 64 + lane];
            acc0 = fmaf(w, hr.x, acc0);
            acc1 = fmaf(w, hr.y, acc1);
        }
    }
    float2 rw = ((const float2*)raw)[(size_t)node * 64 + lane];
    float2 o;
    o.x = fmaf(EPS_C, rw.x, acc0);
    o.y = fmaf(EPS_C, rw.y, acc1);
    ((float2*)hn)[(size_t)node * 64 + lane] = o;
}

// ---------------- output: logits = h @ W2^T + b2, then log_softmax ----------------
__global__ __launch_bounds__(256) void k_out(const float* __restrict__ h, const float* __restrict__ w2,
                                             const float* __restrict__ b2, float* __restrict__ out) {
    __shared__ float w2t[128][40];
    __shared__ float hs[4][128];
    int wid  = threadIdx.x >> 6;
    int lane = threadIdx.x & 63;
    int node = blockIdx.x * 4 + wid;

    for (int idx = threadIdx.x; idx < 40 * 128; idx += 256) {
        int j = idx >> 7;
        int i = idx & 127;
        w2t[i][j] = w2[idx];
    }
    if (node < N_NODES) {
        const float2* hvv = (const float2*)h;
        float2 v = hvv[(size_t)node * 64 + lane];
        hs[wid][2 * lane]     = v.x;
        hs[wid][2 * lane + 1] = v.y;
    }
    __syncthreads();
    if (node < N_NODES) {
        int j = lane;
        float logit = -INFINITY;
        if (j < 40) {
            float a = 0.f;
#pragma unroll 8
            for (int i = 0; i < 128; ++i) a = fmaf(hs[wid][i], w2t[i][j], a);
            logit = a + b2[j];
        }
        float mx = logit;
#pragma unroll
        for (int off = 32; off >= 1; off >>= 1) mx = fmaxf(mx, __shfl_xor(mx, off, 64));
        float ex = (j < 40) ? expf(logit - mx) : 0.f;
        float sum = ex;
#pragma unroll
        for (int off = 32; off >= 1; off >>= 1) sum += __shfl_xor(sum, off, 64);
        float ls = logf(sum);
        if (j < 40) out[(size_t)node * 40 + j] = logit - mx - ls;
    }
}

extern "C" void kernel_launch(void* const* d_in, const int* in_sizes, int n_in,
                              void* d_out, int out_size, void* d_ws, size_t ws_size,
                              hipStream_t stream) {
    const float* x   = (const float*)d_in[0];
    const int*   ei  = (const int*)  d_in[1];
    const float* t1w = (const float*)d_in[2];
    const float* t1b = (const float*)d_in[3];
    const float* gw  = (const float*)d_in[4];
    const float* gb  = (const float*)d_in[5];
    const float* w2  = (const float*)d_in[6];
    const float* b2  = (const float*)d_in[7];
    float* out = (float*)d_out;

    char* p = (char*)d_ws;
    int*   deg      = (int*)p;   p += (size_t)N_NODES * 4;
    int*   cnt      = (int*)p;   p += (size_t)N_NODES * 4;
    int*   fill     = (int*)p;   p += (size_t)N_NODES * 4;
    int*   colptr   = (int*)p;   p += (size_t)(N_NODES + 64) * 4;
    int*   partials = (int*)p;   p += 256 * 4;
    float* nd       = (float*)p; p += (size_t)N_NODES * 4;
    float* dr       = (float*)p; p += (size_t)N_NODES * 4;
    float* dcb      = (float*)p; p += (size_t)N_NODES * 4;
    int2*  csr      = (int2*)p;  p += (size_t)N_EDGES * 8;
    float* wbuf     = (float*)p; p += (size_t)N_EDGES * 4;
    float* h0       = (float*)p; p += (size_t)N_NODES * HIDDEN * 4;
    float* h1       = (float*)p; p += (size_t)N_NODES * HIDDEN * 4;
    float* h2       = (float*)p; p += (size_t)N_NODES * HIDDEN * 4;

    hipMemsetAsync(deg, 0, (size_t)N_NODES * 3 * 4, stream);

    k_count<<<(N_EDGES + 255) / 256, 256, 0, stream>>>(ei, deg, cnt);
    k_nd<<<(N_NODES + 255) / 256, 256, 0, stream>>>(deg, nd);
    int nb = (N_NODES + 1023) / 1024;   // 49
    k_scan_a<<<nb, 256, 0, stream>>>(cnt, colptr, partials);
    k_scan_b<<<1, 64, 0, stream>>>(partials, colptr, nb);
    k_scan_c<<<(N_NODES + 255) / 256, 256, 0, stream>>>(colptr, partials);
    k_scatter<<<(N_EDGES + 255) / 256, 256, 0, stream>>>(ei, colptr, fill, nd, csr);
    k_gemm1<<<(N_NODES + 63) / 64, 256, 0, stream>>>(x, t1w, t1b, h0);

    k_dot <<<(N_NODES + 3) / 4, 256, 0, stream>>>(h0, gw, gb, 0, dr, dcb);
    k_gate<<<(N_NODES + 3) / 4, 256, 0, stream>>>(colptr, csr, dr, dcb, wbuf);
    k_prop<<<(N_NODES + 3) / 4, 256, 0, stream>>>(h0, h0, colptr, csr, wbuf, h1);

    k_dot <<<(N_NODES + 3) / 4, 256, 0, stream>>>(h1, gw, gb, 1, dr, dcb);
    k_gate<<<(N_NODES + 3) / 4, 256, 0, stream>>>(colptr, csr, dr, dcb, wbuf);
    k_prop<<<(N_NODES + 3) / 4, 256, 0, stream>>>(h1, h0, colptr, csr, wbuf, h2);

    k_out<<<(N_NODES + 3) / 4, 256, 0, stream>>>(h2, w2, b2, out);
}

// Round 3
// 829.760 us; speedup vs baseline: 1.1791x; 1.0165x over previous
//
#include <hip/hip_runtime.h>
#include <hip/hip_bf16.h>

#define N_NODES 50000
#define N_EDGES 1600000
#define HIDDEN  128
#define EPS_C   0.3f

typedef __bf16 bf16x8 __attribute__((ext_vector_type(8)));
typedef float  f32x16 __attribute__((ext_vector_type(16)));

// ---------------- degree (over row) + col histogram ----------------
__global__ void k_count(const int* __restrict__ ei, int* __restrict__ deg, int* __restrict__ cnt) {
    int e = blockIdx.x * blockDim.x + threadIdx.x;
    if (e >= N_EDGES) return;
    int r = ei[e];             // row
    int c = ei[N_EDGES + e];   // col
    atomicAdd(&deg[r], 1);
    atomicAdd(&cnt[c], 1);
}

__global__ void k_nd(const int* __restrict__ deg, float* __restrict__ nd) {
    int i = blockIdx.x * blockDim.x + threadIdx.x;
    if (i >= N_NODES) return;
    nd[i] = rsqrtf(fmaxf((float)deg[i], 1.0f));
}

// ---------------- 3-kernel exclusive scan of cnt -> colptr ----------------
__global__ __launch_bounds__(256) void k_scan_a(const int* __restrict__ cnt,
                                                int* __restrict__ out, int* __restrict__ partials) {
    __shared__ int sh[256];
    int t = threadIdx.x;
    int base = blockIdx.x * 1024 + t * 4;
    int v0 = (base + 0 < N_NODES) ? cnt[base + 0] : 0;
    int v1 = (base + 1 < N_NODES) ? cnt[base + 1] : 0;
    int v2 = (base + 2 < N_NODES) ? cnt[base + 2] : 0;
    int v3 = (base + 3 < N_NODES) ? cnt[base + 3] : 0;
    int s = v0 + v1 + v2 + v3;
    sh[t] = s;
    __syncthreads();
    for (int off = 1; off < 256; off <<= 1) {
        int add = (t >= off) ? sh[t - off] : 0;
        __syncthreads();
        sh[t] += add;
        __syncthreads();
    }
    int excl = sh[t] - s;
    if (t == 255) partials[blockIdx.x] = sh[255];
    if (base + 0 < N_NODES) out[base + 0] = excl;
    if (base + 1 < N_NODES) out[base + 1] = excl + v0;
    if (base + 2 < N_NODES) out[base + 2] = excl + v0 + v1;
    if (base + 3 < N_NODES) out[base + 3] = excl + v0 + v1 + v2;
}

__global__ void k_scan_b(int* partials, int* colptr, int nb) {
    if (threadIdx.x == 0 && blockIdx.x == 0) {
        int run = 0;
        for (int i = 0; i < nb; ++i) { int t = partials[i]; partials[i] = run; run += t; }
        colptr[N_NODES] = run;   // == E
    }
}

__global__ void k_scan_c(int* __restrict__ colptr, const int* __restrict__ partials) {
    int i = blockIdx.x * blockDim.x + threadIdx.x;
    if (i >= N_NODES) return;
    colptr[i] += partials[i >> 10];
}

// ---------------- scatter edges into CSR (by col), coef = nd[r]*nd[c] ----------------
__global__ void k_scatter(const int* __restrict__ ei, const int* __restrict__ colptr,
                          int* __restrict__ fill, const float* __restrict__ nd,
                          int2* __restrict__ csr) {
    int e = blockIdx.x * blockDim.x + threadIdx.x;
    if (e >= N_EDGES) return;
    int r = ei[e];
    int c = ei[N_EDGES + e];
    int pos = colptr[c] + atomicAdd(&fill[c], 1);
    int2 v;
    v.x = r;
    v.y = __float_as_int(nd[r] * nd[c]);
    csr[pos] = v;
}

// ---------------- GEMM1: h = relu(x @ W1^T + b1), bf16x3 MFMA, no LDS ----------------
// block = 4 waves over M=64 x N=128; wave tile = M32 x N64 (two 32x32x16 accumulators)
__device__ __forceinline__ void cvt_hilo(const float* v, bf16x8& hi, bf16x8& lo) {
#pragma unroll
    for (int j = 0; j < 8; ++j) {
        float f = v[j];
        __bf16 h = (__bf16)f;
        hi[j] = h;
        lo[j] = (__bf16)(f - (float)h);
    }
}

__global__ __launch_bounds__(256) void k_gemm1(const float* __restrict__ x, const float* __restrict__ w,
                                               const float* __restrict__ bias, float* __restrict__ h) {
    int wave = threadIdx.x >> 6;
    int lane = threadIdx.x & 63;
    int mstrip = wave & 1;        // 0/1 -> m offset 0/32
    int nstrip = wave >> 1;       // 0/1 -> n offset 0/64
    int lm   = lane & 31;
    int half = lane >> 5;

    int m0 = blockIdx.x * 64 + mstrip * 32;
    int m  = m0 + lm;
    int mc = (m < N_NODES) ? m : (N_NODES - 1);   // clamp for loads; stores guarded
    int n0 = nstrip * 64;

    const float* arow  = x + (size_t)mc * 512 + half * 8;
    const float* brow0 = w + (size_t)(n0 + lm) * 512 + half * 8;
    const float* brow1 = brow0 + (size_t)32 * 512;

    f32x16 acc0, acc1;
#pragma unroll
    for (int i = 0; i < 16; ++i) { acc0[i] = 0.f; acc1[i] = 0.f; }

    for (int k0 = 0; k0 < 512; k0 += 16) {
        float4 av0 = *(const float4*)(arow + k0);
        float4 av1 = *(const float4*)(arow + k0 + 4);
        float4 b0v0 = *(const float4*)(brow0 + k0);
        float4 b0v1 = *(const float4*)(brow0 + k0 + 4);
        float4 b1v0 = *(const float4*)(brow1 + k0);
        float4 b1v1 = *(const float4*)(brow1 + k0 + 4);

        float af[8]  = {av0.x, av0.y, av0.z, av0.w, av1.x, av1.y, av1.z, av1.w};
        float b0f[8] = {b0v0.x, b0v0.y, b0v0.z, b0v0.w, b0v1.x, b0v1.y, b0v1.z, b0v1.w};
        float b1f[8] = {b1v0.x, b1v0.y, b1v0.z, b1v0.w, b1v1.x, b1v1.y, b1v1.z, b1v1.w};

        bf16x8 ah, al, b0h, b0l, b1h, b1l;
        cvt_hilo(af, ah, al);
        cvt_hilo(b0f, b0h, b0l);
        cvt_hilo(b1f, b1h, b1l);

        acc0 = __builtin_amdgcn_mfma_f32_32x32x16_bf16(ah, b0h, acc0, 0, 0, 0);
        acc0 = __builtin_amdgcn_mfma_f32_32x32x16_bf16(al, b0h, acc0, 0, 0, 0);
        acc0 = __builtin_amdgcn_mfma_f32_32x32x16_bf16(ah, b0l, acc0, 0, 0, 0);
        acc1 = __builtin_amdgcn_mfma_f32_32x32x16_bf16(ah, b1h, acc1, 0, 0, 0);
        acc1 = __builtin_amdgcn_mfma_f32_32x32x16_bf16(al, b1h, acc1, 0, 0, 0);
        acc1 = __builtin_amdgcn_mfma_f32_32x32x16_bf16(ah, b1l, acc1, 0, 0, 0);
    }

    // epilogue: C layout col=lane&31 (n), row=(reg&3)+8*(reg>>2)+4*half (m)
    float bs0 = bias[n0 + lm];
    float bs1 = bias[n0 + 32 + lm];
#pragma unroll
    for (int reg = 0; reg < 16; ++reg) {
        int row = (reg & 3) + 8 * (reg >> 2) + 4 * half;
        int gm = m0 + row;
        if (gm < N_NODES) {
            h[(size_t)gm * HIDDEN + n0 + lm]      = fmaxf(acc0[reg] + bs0, 0.f);
            h[(size_t)gm * HIDDEN + n0 + 32 + lm] = fmaxf(acc1[reg] + bs1, 0.f);
        }
    }
}

// ---------------- per-node gate dot products: dr = h.w_r, dcb = h.w_c + gb ----------------
__global__ __launch_bounds__(256) void k_dot(const float* __restrict__ h, const float* __restrict__ gw,
                                             const float* __restrict__ gb, int layer,
                                             float* __restrict__ dr, float* __restrict__ dcb) {
    int node = blockIdx.x * 4 + (threadIdx.x >> 6);
    int lane = threadIdx.x & 63;
    if (node >= N_NODES) return;
    const float2* hv = (const float2*)h;
    float2 wr = ((const float2*)(gw + layer * 256))[lane];
    float2 wc = ((const float2*)(gw + layer * 256 + 128))[lane];
    float2 hc = hv[(size_t)node * 64 + lane];
    float a = hc.x * wr.x + hc.y * wr.y;
    float b = hc.x * wc.x + hc.y * wc.y;
#pragma unroll
    for (int off = 32; off >= 1; off >>= 1) {
        a += __shfl_xor(a, off, 64);
        b += __shfl_xor(b, off, 64);
    }
    if (lane == 0) {
        dr[node]  = a;
        dcb[node] = b + gb[layer];
    }
}

// ---------------- per-edge gate weight: w = tanh(dr[row]+dcb[col]) * coef ----------------
__global__ __launch_bounds__(256) void k_gate(const int* __restrict__ colptr, const int2* __restrict__ csr,
                                              const float* __restrict__ dr, const float* __restrict__ dcb,
                                              float* __restrict__ wbuf) {
    int node = blockIdx.x * 4 + (threadIdx.x >> 6);
    int lane = threadIdx.x & 63;
    if (node >= N_NODES) return;
    int beg = colptr[node], end = colptr[node + 1];
    float dc = dcb[node];
    for (int e = beg + lane; e < end; e += 64) {
        int2 ent = csr[e];
        float xx = dr[ent.x] + dc;
        float t = __expf(2.0f * xx);          // saturates to inf / 0, no NaN below
        float g = 1.0f - 2.0f / (t + 1.0f);   // == tanh(xx)
        wbuf[e] = g * __int_as_float(ent.y);
    }
}

// ---------------- propagation: pure weighted gather, wave per node ----------------
__global__ __launch_bounds__(256) void k_prop(const float* __restrict__ h, const float* __restrict__ raw,
                                              const int* __restrict__ colptr, const int2* __restrict__ csr,
                                              const float* __restrict__ wbuf, float* __restrict__ hn) {
    int node = blockIdx.x * 4 + (threadIdx.x >> 6);
    int lane = threadIdx.x & 63;
    if (node >= N_NODES) return;
    const float2* hv = (const float2*)h;
    float acc0 = 0.f, acc1 = 0.f;
    int beg = colptr[node], end = colptr[node + 1];
    for (int base = beg; base < end; base += 64) {
        int e = base + lane;
        int  rr = 0;
        float wv = 0.f;
        if (e < end) {
            rr = csr[e].x;
            wv = wbuf[e];
        }
        int m = end - base; if (m > 64) m = 64;
#pragma unroll 4
        for (int j = 0; j < m; ++j) {
            int   r = __shfl(rr, j, 64);
            float w = __shfl(wv, j, 64);
            float2 hr = hv[(size_t)r * 64 + lane];
            acc0 = fmaf(w, hr.x, acc0);
            acc1 = fmaf(w, hr.y, acc1);
        }
    }
    float2 rw = ((const float2*)raw)[(size_t)node * 64 + lane];
    float2 o;
    o.x = fmaf(EPS_C, rw.x, acc0);
    o.y = fmaf(EPS_C, rw.y, acc1);
    ((float2*)hn)[(size_t)node * 64 + lane] = o;
}

// ---------------- output: logits = h @ W2^T + b2, then log_softmax ----------------
__global__ __launch_bounds__(256) void k_out(const float* __restrict__ h, const float* __restrict__ w2,
                                             const float* __restrict__ b2, float* __restrict__ out) {
    __shared__ float w2t[128][40];
    __shared__ float hs[4][128];
    int wid  = threadIdx.x >> 6;
    int lane = threadIdx.x & 63;
    int node = blockIdx.x * 4 + wid;

    for (int idx = threadIdx.x; idx < 40 * 128; idx += 256) {
        int j = idx >> 7;
        int i = idx & 127;
        w2t[i][j] = w2[idx];
    }
    if (node < N_NODES) {
        const float2* hvv = (const float2*)h;
        float2 v = hvv[(size_t)node * 64 + lane];
        hs[wid][2 * lane]     = v.x;
        hs[wid][2 * lane + 1] = v.y;
    }
    __syncthreads();
    if (node < N_NODES) {
        int j = lane;
        float logit = -INFINITY;
        if (j < 40) {
            float a = 0.f;
#pragma unroll 8
            for (int i = 0; i < 128; ++i) a = fmaf(hs[wid][i], w2t[i][j], a);
            logit = a + b2[j];
        }
        float mx = logit;
#pragma unroll
        for (int off = 32; off >= 1; off >>= 1) mx = fmaxf(mx, __shfl_xor(mx, off, 64));
        float ex = (j < 40) ? expf(logit - mx) : 0.f;
        float sum = ex;
#pragma unroll
        for (int off = 32; off >= 1; off >>= 1) sum += __shfl_xor(sum, off, 64);
        float ls = logf(sum);
        if (j < 40) out[(size_t)node * 40 + j] = logit - mx - ls;
    }
}

extern "C" void kernel_launch(void* const* d_in, const int* in_sizes, int n_in,
                              void* d_out, int out_size, void* d_ws, size_t ws_size,
                              hipStream_t stream) {
    const float* x   = (const float*)d_in[0];
    const int*   ei  = (const int*)  d_in[1];
    const float* t1w = (const float*)d_in[2];
    const float* t1b = (const float*)d_in[3];
    const float* gw  = (const float*)d_in[4];
    const float* gb  = (const float*)d_in[5];
    const float* w2  = (const float*)d_in[6];
    const float* b2  = (const float*)d_in[7];
    float* out = (float*)d_out;

    char* p = (char*)d_ws;
    int*   deg      = (int*)p;   p += (size_t)N_NODES * 4;
    int*   cnt      = (int*)p;   p += (size_t)N_NODES * 4;
    int*   fill     = (int*)p;   p += (size_t)N_NODES * 4;
    int*   colptr   = (int*)p;   p += (size_t)(N_NODES + 64) * 4;
    int*   partials = (int*)p;   p += 256 * 4;
    float* nd       = (float*)p; p += (size_t)N_NODES * 4;
    float* dr       = (float*)p; p += (size_t)N_NODES * 4;
    float* dcb      = (float*)p; p += (size_t)N_NODES * 4;
    int2*  csr      = (int2*)p;  p += (size_t)N_EDGES * 8;
    float* wbuf     = (float*)p; p += (size_t)N_EDGES * 4;
    float* h0       = (float*)p; p += (size_t)N_NODES * HIDDEN * 4;
    float* h1       = (float*)p; p += (size_t)N_NODES * HIDDEN * 4;
    float* h2       = (float*)p; p += (size_t)N_NODES * HIDDEN * 4;

    hipMemsetAsync(deg, 0, (size_t)N_NODES * 3 * 4, stream);

    k_count<<<(N_EDGES + 255) / 256, 256, 0, stream>>>(ei, deg, cnt);
    k_nd<<<(N_NODES + 255) / 256, 256, 0, stream>>>(deg, nd);
    int nb = (N_NODES + 1023) / 1024;   // 49
    k_scan_a<<<nb, 256, 0, stream>>>(cnt, colptr, partials);
    k_scan_b<<<1, 64, 0, stream>>>(partials, colptr, nb);
    k_scan_c<<<(N_NODES + 255) / 256, 256, 0, stream>>>(colptr, partials);
    k_scatter<<<(N_EDGES + 255) / 256, 256, 0, stream>>>(ei, colptr, fill, nd, csr);
    k_gemm1<<<(N_NODES + 63) / 64, 256, 0, stream>>>(x, t1w, t1b, h0);

    k_dot <<<(N_NODES + 3) / 4, 256, 0, stream>>>(h0, gw, gb, 0, dr, dcb);
    k_gate<<<(N_NODES + 3) / 4, 256, 0, stream>>>(colptr, csr, dr, dcb, wbuf);
    k_prop<<<(N_NODES + 3) / 4, 256, 0, stream>>>(h0, h0, colptr, csr, wbuf, h1);

    k_dot <<<(N_NODES + 3) / 4, 256, 0, stream>>>(h1, gw, gb, 1, dr, dcb);
    k_gate<<<(N_NODES + 3) / 4, 256, 0, stream>>>(colptr, csr, dr, dcb, wbuf);
    k_prop<<<(N_NODES + 3) / 4, 256, 0, stream>>>(h1, h0, colptr, csr, wbuf, h2);

    k_out<<<(N_NODES + 3) / 4, 256, 0, stream>>>(h2, w2, b2, out);
}

// Round 4
// 776.772 us; speedup vs baseline: 1.2595x; 1.0682x over previous
//
#include <hip/hip_runtime.h>
#include <hip/hip_bf16.h>
#include <hip/hip_fp16.h>

#define N_NODES 50000
#define N_EDGES 1600000
#define HIDDEN  128
#define EPS_C   0.3f

typedef _Float16 f16x8 __attribute__((ext_vector_type(8)));
typedef float    f32x16 __attribute__((ext_vector_type(16)));

// ---------------- degree (over row) + col histogram ----------------
__global__ void k_count(const int* __restrict__ ei, int* __restrict__ deg, int* __restrict__ cnt) {
    int e = blockIdx.x * blockDim.x + threadIdx.x;
    if (e >= N_EDGES) return;
    int r = ei[e];             // row
    int c = ei[N_EDGES + e];   // col
    atomicAdd(&deg[r], 1);
    atomicAdd(&cnt[c], 1);
}

__global__ void k_nd(const int* __restrict__ deg, float* __restrict__ nd) {
    int i = blockIdx.x * blockDim.x + threadIdx.x;
    if (i >= N_NODES) return;
    nd[i] = rsqrtf(fmaxf((float)deg[i], 1.0f));
}

// ---------------- 3-kernel exclusive scan of cnt -> colptr ----------------
__global__ __launch_bounds__(256) void k_scan_a(const int* __restrict__ cnt,
                                                int* __restrict__ out, int* __restrict__ partials) {
    __shared__ int sh[256];
    int t = threadIdx.x;
    int base = blockIdx.x * 1024 + t * 4;
    int v0 = (base + 0 < N_NODES) ? cnt[base + 0] : 0;
    int v1 = (base + 1 < N_NODES) ? cnt[base + 1] : 0;
    int v2 = (base + 2 < N_NODES) ? cnt[base + 2] : 0;
    int v3 = (base + 3 < N_NODES) ? cnt[base + 3] : 0;
    int s = v0 + v1 + v2 + v3;
    sh[t] = s;
    __syncthreads();
    for (int off = 1; off < 256; off <<= 1) {
        int add = (t >= off) ? sh[t - off] : 0;
        __syncthreads();
        sh[t] += add;
        __syncthreads();
    }
    int excl = sh[t] - s;
    if (t == 255) partials[blockIdx.x] = sh[255];
    if (base + 0 < N_NODES) out[base + 0] = excl;
    if (base + 1 < N_NODES) out[base + 1] = excl + v0;
    if (base + 2 < N_NODES) out[base + 2] = excl + v0 + v1;
    if (base + 3 < N_NODES) out[base + 3] = excl + v0 + v1 + v2;
}

__global__ void k_scan_b(int* partials, int* colptr, int nb) {
    if (threadIdx.x == 0 && blockIdx.x == 0) {
        int run = 0;
        for (int i = 0; i < nb; ++i) { int t = partials[i]; partials[i] = run; run += t; }
        colptr[N_NODES] = run;   // == E
    }
}

__global__ void k_scan_c(int* __restrict__ colptr, const int* __restrict__ partials) {
    int i = blockIdx.x * blockDim.x + threadIdx.x;
    if (i >= N_NODES) return;
    colptr[i] += partials[i >> 10];
}

// ---------------- scatter edges into CSR (by col): store row only ----------------
__global__ void k_scatter(const int* __restrict__ ei, const int* __restrict__ colptr,
                          int* __restrict__ fill, int* __restrict__ csr) {
    int e = blockIdx.x * blockDim.x + threadIdx.x;
    if (e >= N_EDGES) return;
    int r = ei[e];
    int c = ei[N_EDGES + e];
    int pos = colptr[c] + atomicAdd(&fill[c], 1);
    csr[pos] = r;
}

// ---------------- generic fp32 -> fp16 convert (n4 = count of float4) ----------------
__global__ void k_cvt(const float4* __restrict__ src, __half2* __restrict__ dst, int n4) {
    int i = blockIdx.x * 256 + threadIdx.x;
    if (i >= n4) return;
    float4 v = src[i];
    dst[2 * i]     = __floats2half2_rn(v.x, v.y);
    dst[2 * i + 1] = __floats2half2_rn(v.z, v.w);
}

// ---------------- GEMM1: h = relu(x @ W1^T + b1), fp16 single-pass MFMA ----------------
// block = 4 waves over M=64 x N=128; wave tile = M32 x N64 (two 32x32x16 accumulators)
__global__ __launch_bounds__(256) void k_gemm1(const _Float16* __restrict__ xh, const _Float16* __restrict__ wh,
                                               const float* __restrict__ bias, float* __restrict__ h) {
    int wave = threadIdx.x >> 6;
    int lane = threadIdx.x & 63;
    int mstrip = wave & 1;
    int nstrip = wave >> 1;
    int lm   = lane & 31;
    int half = lane >> 5;

    int m0 = blockIdx.x * 64 + mstrip * 32;
    int m  = m0 + lm;
    int mc = (m < N_NODES) ? m : (N_NODES - 1);   // clamp for loads; stores guarded
    int n0 = nstrip * 64;

    const _Float16* arow  = xh + (size_t)mc * 512 + half * 8;
    const _Float16* brow0 = wh + (size_t)(n0 + lm) * 512 + half * 8;
    const _Float16* brow1 = brow0 + (size_t)32 * 512;

    f32x16 acc0, acc1;
#pragma unroll
    for (int i = 0; i < 16; ++i) { acc0[i] = 0.f; acc1[i] = 0.f; }

#pragma unroll 4
    for (int k0 = 0; k0 < 512; k0 += 16) {
        f16x8 av = *(const f16x8*)(arow  + k0);
        f16x8 b0 = *(const f16x8*)(brow0 + k0);
        f16x8 b1 = *(const f16x8*)(brow1 + k0);
        acc0 = __builtin_amdgcn_mfma_f32_32x32x16_f16(av, b0, acc0, 0, 0, 0);
        acc1 = __builtin_amdgcn_mfma_f32_32x32x16_f16(av, b1, acc1, 0, 0, 0);
    }

    // epilogue: C layout col=lane&31 (n), row=(reg&3)+8*(reg>>2)+4*half (m)
    float bs0 = bias[n0 + lm];
    float bs1 = bias[n0 + 32 + lm];
#pragma unroll
    for (int reg = 0; reg < 16; ++reg) {
        int row = (reg & 3) + 8 * (reg >> 2) + 4 * half;
        int gm = m0 + row;
        if (gm < N_NODES) {
            h[(size_t)gm * HIDDEN + n0 + lm]      = fmaxf(acc0[reg] + bs0, 0.f);
            h[(size_t)gm * HIDDEN + n0 + 32 + lm] = fmaxf(acc1[reg] + bs1, 0.f);
        }
    }
}

// ---------------- per-node gate dots: dn = {h.w_r, nd}, dcb = h.w_c + gb ----------------
__global__ __launch_bounds__(256) void k_dot(const float* __restrict__ h, const float* __restrict__ gw,
                                             const float* __restrict__ gb, const float* __restrict__ nd,
                                             int layer, float2* __restrict__ dn, float* __restrict__ dcb) {
    int node = blockIdx.x * 4 + (threadIdx.x >> 6);
    int lane = threadIdx.x & 63;
    if (node >= N_NODES) return;
    const float2* hv = (const float2*)h;
    float2 wr = ((const float2*)(gw + layer * 256))[lane];
    float2 wc = ((const float2*)(gw + layer * 256 + 128))[lane];
    float2 hc = hv[(size_t)node * 64 + lane];
    float a = hc.x * wr.x + hc.y * wr.y;
    float b = hc.x * wc.x + hc.y * wc.y;
#pragma unroll
    for (int off = 32; off >= 1; off >>= 1) {
        a += __shfl_xor(a, off, 64);
        b += __shfl_xor(b, off, 64);
    }
    if (lane == 0) {
        dn[node]  = make_float2(a, nd[node]);
        dcb[node] = b + gb[layer];
    }
}

// ---------------- per-edge gate weight: ew = {row, tanh(dr[row]+dcb)*nd_r*nd_c} ----------------
__global__ __launch_bounds__(256) void k_gate(const int* __restrict__ colptr, const int* __restrict__ csr,
                                              const float2* __restrict__ dn, const float* __restrict__ dcb,
                                              const float* __restrict__ nd, int2* __restrict__ ew) {
    int node = blockIdx.x * 4 + (threadIdx.x >> 6);
    int lane = threadIdx.x & 63;
    if (node >= N_NODES) return;
    int beg = colptr[node], end = colptr[node + 1];
    float dc  = dcb[node];
    float ndc = nd[node];
    for (int e = beg + lane; e < end; e += 64) {
        int r = csr[e];
        float2 v = dn[r];
        float xx = v.x + dc;
        float t = __expf(2.0f * xx);          // saturates to inf / 0, no NaN below
        float g = 1.0f - 2.0f / (t + 1.0f);   // == tanh(xx)
        int2 o;
        o.x = r;
        o.y = __float_as_int(g * v.y * ndc);
        ew[e] = o;
    }
}

// ---------------- propagation: weighted gather from fp16 h, wave per node ----------------
__global__ __launch_bounds__(256) void k_prop(const __half2* __restrict__ hb, const float* __restrict__ raw,
                                              const int* __restrict__ colptr, const int2* __restrict__ ew,
                                              float* __restrict__ hn, __half2* __restrict__ hbn) {
    int node = blockIdx.x * 4 + (threadIdx.x >> 6);
    int lane = threadIdx.x & 63;
    if (node >= N_NODES) return;
    float acc0 = 0.f, acc1 = 0.f;
    int beg = colptr[node], end = colptr[node + 1];
    for (int base = beg; base < end; base += 64) {
        int e = base + lane;
        int  rr = 0;
        float wv = 0.f;
        if (e < end) {
            int2 p = ew[e];
            rr = p.x;
            wv = __int_as_float(p.y);
        }
        int m = end - base; if (m > 64) m = 64;
#pragma unroll 4
        for (int j = 0; j < m; ++j) {
            int   r = __shfl(rr, j, 64);
            float w = __shfl(wv, j, 64);
            float2 hf = __half22float2(hb[(size_t)r * 64 + lane]);
            acc0 = fmaf(w, hf.x, acc0);
            acc1 = fmaf(w, hf.y, acc1);
        }
    }
    float2 rw = ((const float2*)raw)[(size_t)node * 64 + lane];
    float2 o;
    o.x = fmaf(EPS_C, rw.x, acc0);
    o.y = fmaf(EPS_C, rw.y, acc1);
    ((float2*)hn)[(size_t)node * 64 + lane] = o;
    hbn[(size_t)node * 64 + lane] = __floats2half2_rn(o.x, o.y);
}

// ---------------- output: logits = h @ W2^T + b2, then log_softmax ----------------
__global__ __launch_bounds__(256) void k_out(const float* __restrict__ h, const float* __restrict__ w2,
                                             const float* __restrict__ b2, float* __restrict__ out) {
    __shared__ float w2t[128][40];
    __shared__ float hs[4][128];
    int wid  = threadIdx.x >> 6;
    int lane = threadIdx.x & 63;
    int node = blockIdx.x * 4 + wid;

    for (int idx = threadIdx.x; idx < 40 * 128; idx += 256) {
        int j = idx >> 7;
        int i = idx & 127;
        w2t[i][j] = w2[idx];
    }
    if (node < N_NODES) {
        const float2* hvv = (const float2*)h;
        float2 v = hvv[(size_t)node * 64 + lane];
        hs[wid][2 * lane]     = v.x;
        hs[wid][2 * lane + 1] = v.y;
    }
    __syncthreads();
    if (node < N_NODES) {
        int j = lane;
        float logit = -INFINITY;
        if (j < 40) {
            float a = 0.f;
#pragma unroll 8
            for (int i = 0; i < 128; ++i) a = fmaf(hs[wid][i], w2t[i][j], a);
            logit = a + b2[j];
        }
        float mx = logit;
#pragma unroll
        for (int off = 32; off >= 1; off >>= 1) mx = fmaxf(mx, __shfl_xor(mx, off, 64));
        float ex = (j < 40) ? expf(logit - mx) : 0.f;
        float sum = ex;
#pragma unroll
        for (int off = 32; off >= 1; off >>= 1) sum += __shfl_xor(sum, off, 64);
        float ls = logf(sum);
        if (j < 40) out[(size_t)node * 40 + j] = logit - mx - ls;
    }
}

extern "C" void kernel_launch(void* const* d_in, const int* in_sizes, int n_in,
                              void* d_out, int out_size, void* d_ws, size_t ws_size,
                              hipStream_t stream) {
    const float* x   = (const float*)d_in[0];
    const int*   ei  = (const int*)  d_in[1];
    const float* t1w = (const float*)d_in[2];
    const float* t1b = (const float*)d_in[3];
    const float* gw  = (const float*)d_in[4];
    const float* gb  = (const float*)d_in[5];
    const float* w2  = (const float*)d_in[6];
    const float* b2  = (const float*)d_in[7];
    float* out = (float*)d_out;

    char* p = (char*)d_ws;
    int*    deg      = (int*)p;    p += (size_t)N_NODES * 4;
    int*    cnt      = (int*)p;    p += (size_t)N_NODES * 4;
    int*    fill     = (int*)p;    p += (size_t)N_NODES * 4;
    int*    colptr   = (int*)p;    p += (size_t)(N_NODES + 64) * 4;
    int*    partials = (int*)p;    p += 256 * 4;
    float*  nd       = (float*)p;  p += (size_t)N_NODES * 4;
    float*  dcb      = (float*)p;  p += (size_t)N_NODES * 4;
    float2* dn       = (float2*)p; p += (size_t)N_NODES * 8;
    int*    csr      = (int*)p;    p += (size_t)N_EDGES * 4;
    int2*   ew       = (int2*)p;   p += (size_t)N_EDGES * 8;
    __half2* hb0     = (__half2*)p; p += (size_t)N_NODES * 64 * 4;
    __half2* hb1     = (__half2*)p; p += (size_t)N_NODES * 64 * 4;
    float*  h0       = (float*)p;  p += (size_t)N_NODES * HIDDEN * 4;
    _Float16* xh     = (_Float16*)p;                          // 51.2 MB region
    float*  h1       = (float*)p;  p += (size_t)N_NODES * HIDDEN * 4;   // aliases xh (dead after gemm1)
    float*  h2       = (float*)p;  p += (size_t)N_NODES * HIDDEN * 4;   // aliases xh upper half
    _Float16* wh     = (_Float16*)p; p += (size_t)HIDDEN * 512 * 2;

    hipMemsetAsync(deg, 0, (size_t)N_NODES * 3 * 4, stream);

    k_count<<<(N_EDGES + 255) / 256, 256, 0, stream>>>(ei, deg, cnt);
    k_nd<<<(N_NODES + 255) / 256, 256, 0, stream>>>(deg, nd);
    int nb = (N_NODES + 1023) / 1024;   // 49
    k_scan_a<<<nb, 256, 0, stream>>>(cnt, colptr, partials);
    k_scan_b<<<1, 64, 0, stream>>>(partials, colptr, nb);
    k_scan_c<<<(N_NODES + 255) / 256, 256, 0, stream>>>(colptr, partials);
    k_scatter<<<(N_EDGES + 255) / 256, 256, 0, stream>>>(ei, colptr, fill, csr);

    // convert x and w to fp16, run MFMA GEMM
    k_cvt<<<(6400000 + 255) / 256, 256, 0, stream>>>((const float4*)x,   (__half2*)xh, 6400000);
    k_cvt<<<(16384 + 255) / 256,  256, 0, stream>>>((const float4*)t1w, (__half2*)wh, 16384);
    k_gemm1<<<(N_NODES + 63) / 64, 256, 0, stream>>>(xh, wh, t1b, h0);
    // h0 -> fp16 copy for the gather path (xh is dead from here; h1/h2 alias it)
    k_cvt<<<(1600000 + 255) / 256, 256, 0, stream>>>((const float4*)h0, hb0, 1600000);

    k_dot <<<(N_NODES + 3) / 4, 256, 0, stream>>>(h0, gw, gb, nd, 0, dn, dcb);
    k_gate<<<(N_NODES + 3) / 4, 256, 0, stream>>>(colptr, csr, dn, dcb, nd, ew);
    k_prop<<<(N_NODES + 3) / 4, 256, 0, stream>>>(hb0, h0, colptr, ew, h1, hb1);

    k_dot <<<(N_NODES + 3) / 4, 256, 0, stream>>>(h1, gw, gb, nd, 1, dn, dcb);
    k_gate<<<(N_NODES + 3) / 4, 256, 0, stream>>>(colptr, csr, dn, dcb, nd, ew);
    k_prop<<<(N_NODES + 3) / 4, 256, 0, stream>>>(hb1, h0, colptr, ew, h2, hb0);

    k_out<<<(N_NODES + 3) / 4, 256, 0, stream>>>(h2, w2, b2, out);
}

// Round 5
// 662.310 us; speedup vs baseline: 1.4772x; 1.1728x over previous
//
#include <hip/hip_runtime.h>
#include <hip/hip_bf16.h>
#include <hip/hip_fp16.h>

#define N_NODES 50000
#define N_EDGES 1600000
#define HIDDEN  128
#define EPS_C   0.3f
#define NWORDS  12500      // 50000 nodes, 4 u8 counters per u32 word
#define CHUNK   25000      // edges per histogram block; 64 chunks = 1.6M
#define NCHUNK  64

typedef _Float16 f16x8 __attribute__((ext_vector_type(8)));
typedef float    f32x16 __attribute__((ext_vector_type(16)));

// ---------------- per-chunk LDS histograms (u8-packed), zero global atomics ----------------
// grid 128: blocks 0..63 count rows (deg), 64..127 count cols (cnt)
__global__ __launch_bounds__(256) void k_hist(const int* __restrict__ ei, unsigned int* __restrict__ part) {
    __shared__ unsigned int hist[NWORDS];   // 50 KB
    int b = blockIdx.x;
    int type  = b >> 6;
    int chunk = b & 63;
    const int* src = ei + (size_t)type * N_EDGES + (size_t)chunk * CHUNK;
    for (int i = threadIdx.x; i < NWORDS; i += 256) hist[i] = 0;
    __syncthreads();
    for (int i = threadIdx.x; i < CHUNK; i += 256) {
        int v = src[i];
        atomicAdd(&hist[v >> 2], 1u << ((v & 3) * 8));
    }
    __syncthreads();
    unsigned int* dst = part + ((size_t)type * NCHUNK + chunk) * NWORDS;
    for (int i = threadIdx.x; i < NWORDS; i += 256) dst[i] = hist[i];
}

// ---------------- reduce partials -> nd, cnt, and per-(chunk,col) exclusive prefix ----------------
__global__ __launch_bounds__(256) void k_reduce(const unsigned int* __restrict__ part,
                                                float* __restrict__ nd, int* __restrict__ cnt,
                                                unsigned short* __restrict__ cntpre) {
    int w = blockIdx.x * 256 + threadIdx.x;
    if (w >= NWORDS) return;
    // deg (rows)
    unsigned int s0 = 0, s1 = 0, s2 = 0, s3 = 0;
    const unsigned int* dp = part + w;
    for (int b = 0; b < NCHUNK; ++b) {
        unsigned int v = dp[(size_t)b * NWORDS];
        s0 += v & 255u; s1 += (v >> 8) & 255u; s2 += (v >> 16) & 255u; s3 += v >> 24;
    }
    nd[4 * w + 0] = rsqrtf(fmaxf((float)s0, 1.f));
    nd[4 * w + 1] = rsqrtf(fmaxf((float)s1, 1.f));
    nd[4 * w + 2] = rsqrtf(fmaxf((float)s2, 1.f));
    nd[4 * w + 3] = rsqrtf(fmaxf((float)s3, 1.f));
    // cnt (cols) + exclusive prefix per chunk
    const unsigned int* cp = part + (size_t)NCHUNK * NWORDS + w;
    unsigned int r0 = 0, r1 = 0, r2 = 0, r3 = 0;
    for (int b = 0; b < NCHUNK; ++b) {
        size_t o = (size_t)b * N_NODES + 4 * w;
        *(ushort4*)&cntpre[o] = make_ushort4((unsigned short)r0, (unsigned short)r1,
                                             (unsigned short)r2, (unsigned short)r3);
        unsigned int v = cp[(size_t)b * NWORDS];
        r0 += v & 255u; r1 += (v >> 8) & 255u; r2 += (v >> 16) & 255u; r3 += v >> 24;
    }
    cnt[4 * w + 0] = (int)r0;
    cnt[4 * w + 1] = (int)r1;
    cnt[4 * w + 2] = (int)r2;
    cnt[4 * w + 3] = (int)r3;
}

// ---------------- 3-kernel exclusive scan of cnt -> colptr ----------------
__global__ __launch_bounds__(256) void k_scan_a(const int* __restrict__ cnt,
                                                int* __restrict__ out, int* __restrict__ partials) {
    __shared__ int sh[256];
    int t = threadIdx.x;
    int base = blockIdx.x * 1024 + t * 4;
    int v0 = (base + 0 < N_NODES) ? cnt[base + 0] : 0;
    int v1 = (base + 1 < N_NODES) ? cnt[base + 1] : 0;
    int v2 = (base + 2 < N_NODES) ? cnt[base + 2] : 0;
    int v3 = (base + 3 < N_NODES) ? cnt[base + 3] : 0;
    int s = v0 + v1 + v2 + v3;
    sh[t] = s;
    __syncthreads();
    for (int off = 1; off < 256; off <<= 1) {
        int add = (t >= off) ? sh[t - off] : 0;
        __syncthreads();
        sh[t] += add;
        __syncthreads();
    }
    int excl = sh[t] - s;
    if (t == 255) partials[blockIdx.x] = sh[255];
    if (base + 0 < N_NODES) out[base + 0] = excl;
    if (base + 1 < N_NODES) out[base + 1] = excl + v0;
    if (base + 2 < N_NODES) out[base + 2] = excl + v0 + v1;
    if (base + 3 < N_NODES) out[base + 3] = excl + v0 + v1 + v2;
}

__global__ void k_scan_b(int* partials, int* colptr, int nb) {
    if (threadIdx.x == 0 && blockIdx.x == 0) {
        int run = 0;
        for (int i = 0; i < nb; ++i) { int t = partials[i]; partials[i] = run; run += t; }
        colptr[N_NODES] = run;   // == E
    }
}

__global__ void k_scan_c(int* __restrict__ colptr, const int* __restrict__ partials) {
    int i = blockIdx.x * blockDim.x + threadIdx.x;
    if (i >= N_NODES) return;
    colptr[i] += partials[i >> 10];
}

// ---------------- scatter via LDS rank, zero global atomics ----------------
__global__ __launch_bounds__(256) void k_scatter2(const int* __restrict__ ei, const int* __restrict__ colptr,
                                                  const unsigned short* __restrict__ cntpre,
                                                  int* __restrict__ csr) {
    __shared__ unsigned int rank[NWORDS];   // 50 KB
    int b = blockIdx.x;
    for (int i = threadIdx.x; i < NWORDS; i += 256) rank[i] = 0;
    __syncthreads();
    const int* rs = ei + (size_t)b * CHUNK;
    const int* cs = ei + N_EDGES + (size_t)b * CHUNK;
    const unsigned short* pre = cntpre + (size_t)b * N_NODES;
    for (int i = threadIdx.x; i < CHUNK; i += 256) {
        int r = rs[i];
        int c = cs[i];
        unsigned int old = atomicAdd(&rank[c >> 2], 1u << ((c & 3) * 8));
        unsigned int lr = (old >> ((c & 3) * 8)) & 255u;
        int pos = colptr[c] + (int)pre[c] + (int)lr;
        csr[pos] = r;
    }
}

// ---------------- fp32 -> fp16 convert (n4 = count of float4) ----------------
__global__ void k_cvt(const float4* __restrict__ src, __half2* __restrict__ dst, int n4) {
    int i = blockIdx.x * 256 + threadIdx.x;
    if (i >= n4) return;
    float4 v = src[i];
    dst[2 * i]     = __floats2half2_rn(v.x, v.y);
    dst[2 * i + 1] = __floats2half2_rn(v.z, v.w);
}

// ---------------- GEMM1: h = relu(x @ W1^T + b1), fp16 MFMA, fused fp16 output ----------------
// block = 4 waves over M=64 x N=128; wave tile = M32 x N64 (two 32x32x16 accumulators)
__global__ __launch_bounds__(256) void k_gemm1(const float* __restrict__ x, const _Float16* __restrict__ wh,
                                               const float* __restrict__ bias, float* __restrict__ h,
                                               _Float16* __restrict__ hb) {
    int wave = threadIdx.x >> 6;
    int lane = threadIdx.x & 63;
    int mstrip = wave & 1;
    int nstrip = wave >> 1;
    int lm   = lane & 31;
    int half = lane >> 5;

    int m0 = blockIdx.x * 64 + mstrip * 32;
    int m  = m0 + lm;
    int mc = (m < N_NODES) ? m : (N_NODES - 1);   // clamp for loads; stores guarded
    int n0 = nstrip * 64;

    const float*    arow  = x  + (size_t)mc * 512 + half * 8;
    const _Float16* brow0 = wh + (size_t)(n0 + lm) * 512 + half * 8;
    const _Float16* brow1 = brow0 + (size_t)32 * 512;

    f32x16 acc0, acc1;
#pragma unroll
    for (int i = 0; i < 16; ++i) { acc0[i] = 0.f; acc1[i] = 0.f; }

#pragma unroll 4
    for (int k0 = 0; k0 < 512; k0 += 16) {
        float4 a0 = *(const float4*)(arow + k0);
        float4 a1 = *(const float4*)(arow + k0 + 4);
        f16x8 av;
        av[0] = (_Float16)a0.x; av[1] = (_Float16)a0.y; av[2] = (_Float16)a0.z; av[3] = (_Float16)a0.w;
        av[4] = (_Float16)a1.x; av[5] = (_Float16)a1.y; av[6] = (_Float16)a1.z; av[7] = (_Float16)a1.w;
        f16x8 b0 = *(const f16x8*)(brow0 + k0);
        f16x8 b1 = *(const f16x8*)(brow1 + k0);
        acc0 = __builtin_amdgcn_mfma_f32_32x32x16_f16(av, b0, acc0, 0, 0, 0);
        acc1 = __builtin_amdgcn_mfma_f32_32x32x16_f16(av, b1, acc1, 0, 0, 0);
    }

    // epilogue: C layout col=lane&31 (n), row=(reg&3)+8*(reg>>2)+4*half (m)
    float bs0 = bias[n0 + lm];
    float bs1 = bias[n0 + 32 + lm];
#pragma unroll
    for (int reg = 0; reg < 16; ++reg) {
        int row = (reg & 3) + 8 * (reg >> 2) + 4 * half;
        int gm = m0 + row;
        if (gm < N_NODES) {
            float v0 = fmaxf(acc0[reg] + bs0, 0.f);
            float v1 = fmaxf(acc1[reg] + bs1, 0.f);
            h[(size_t)gm * HIDDEN + n0 + lm]      = v0;
            h[(size_t)gm * HIDDEN + n0 + 32 + lm] = v1;
            hb[(size_t)gm * HIDDEN + n0 + lm]      = (_Float16)v0;
            hb[(size_t)gm * HIDDEN + n0 + 32 + lm] = (_Float16)v1;
        }
    }
}

// ---------------- per-node gate dots: dn = {h.w_r, nd}, dcb = h.w_c + gb ----------------
__global__ __launch_bounds__(256) void k_dot(const float* __restrict__ h, const float* __restrict__ gw,
                                             const float* __restrict__ gb, const float* __restrict__ nd,
                                             int layer, float2* __restrict__ dn, float* __restrict__ dcb) {
    int node = blockIdx.x * 4 + (threadIdx.x >> 6);
    int lane = threadIdx.x & 63;
    if (node >= N_NODES) return;
    const float2* hv = (const float2*)h;
    float2 wr = ((const float2*)(gw + layer * 256))[lane];
    float2 wc = ((const float2*)(gw + layer * 256 + 128))[lane];
    float2 hc = hv[(size_t)node * 64 + lane];
    float a = hc.x * wr.x + hc.y * wr.y;
    float b = hc.x * wc.x + hc.y * wc.y;
#pragma unroll
    for (int off = 32; off >= 1; off >>= 1) {
        a += __shfl_xor(a, off, 64);
        b += __shfl_xor(b, off, 64);
    }
    if (lane == 0) {
        dn[node]  = make_float2(a, nd[node]);
        dcb[node] = b + gb[layer];
    }
}

// ---------------- propagation with fused gate: wave per node ----------------
__global__ __launch_bounds__(256) void k_prop(const __half2* __restrict__ hb, const float* __restrict__ raw,
                                              const int* __restrict__ colptr, const int* __restrict__ csr,
                                              const float2* __restrict__ dn, const float* __restrict__ dcb,
                                              const float* __restrict__ nd,
                                              float* __restrict__ hn, __half2* __restrict__ hbn) {
    int node = blockIdx.x * 4 + (threadIdx.x >> 6);
    int lane = threadIdx.x & 63;
    if (node >= N_NODES) return;
    float dc  = dcb[node];
    float ndc = nd[node];
    float acc0 = 0.f, acc1 = 0.f;
    int beg = colptr[node], end = colptr[node + 1];
    for (int base = beg; base < end; base += 64) {
        int e = base + lane;
        int  rr = 0;
        float wv = 0.f;
        if (e < end) {
            rr = csr[e];
            float2 v = dn[rr];
            float xx = v.x + dc;
            float t = __expf(2.0f * xx);          // saturates to inf / 0, no NaN below
            float g = 1.0f - 2.0f / (t + 1.0f);   // == tanh(xx)
            wv = g * v.y * ndc;
        }
        int m = end - base; if (m > 64) m = 64;
#pragma unroll 4
        for (int j = 0; j < m; ++j) {
            int   r = __shfl(rr, j, 64);
            float w = __shfl(wv, j, 64);
            float2 hf = __half22float2(hb[(size_t)r * 64 + lane]);
            acc0 = fmaf(w, hf.x, acc0);
            acc1 = fmaf(w, hf.y, acc1);
        }
    }
    float2 rw = ((const float2*)raw)[(size_t)node * 64 + lane];
    float2 o;
    o.x = fmaf(EPS_C, rw.x, acc0);
    o.y = fmaf(EPS_C, rw.y, acc1);
    ((float2*)hn)[(size_t)node * 64 + lane] = o;
    hbn[(size_t)node * 64 + lane] = __floats2half2_rn(o.x, o.y);
}

// ---------------- output: logits = h @ W2^T + b2, then log_softmax ----------------
__global__ __launch_bounds__(256) void k_out(const float* __restrict__ h, const float* __restrict__ w2,
                                             const float* __restrict__ b2, float* __restrict__ out) {
    __shared__ float w2t[128][40];
    __shared__ float hs[4][128];
    int wid  = threadIdx.x >> 6;
    int lane = threadIdx.x & 63;
    int node = blockIdx.x * 4 + wid;

    for (int idx = threadIdx.x; idx < 40 * 128; idx += 256) {
        int j = idx >> 7;
        int i = idx & 127;
        w2t[i][j] = w2[idx];
    }
    if (node < N_NODES) {
        const float2* hvv = (const float2*)h;
        float2 v = hvv[(size_t)node * 64 + lane];
        hs[wid][2 * lane]     = v.x;
        hs[wid][2 * lane + 1] = v.y;
    }
    __syncthreads();
    if (node < N_NODES) {
        int j = lane;
        float logit = -INFINITY;
        if (j < 40) {
            float a = 0.f;
#pragma unroll 8
            for (int i = 0; i < 128; ++i) a = fmaf(hs[wid][i], w2t[i][j], a);
            logit = a + b2[j];
        }
        float mx = logit;
#pragma unroll
        for (int off = 32; off >= 1; off >>= 1) mx = fmaxf(mx, __shfl_xor(mx, off, 64));
        float ex = (j < 40) ? expf(logit - mx) : 0.f;
        float sum = ex;
#pragma unroll
        for (int off = 32; off >= 1; off >>= 1) sum += __shfl_xor(sum, off, 64);
        float ls = logf(sum);
        if (j < 40) out[(size_t)node * 40 + j] = logit - mx - ls;
    }
}

extern "C" void kernel_launch(void* const* d_in, const int* in_sizes, int n_in,
                              void* d_out, int out_size, void* d_ws, size_t ws_size,
                              hipStream_t stream) {
    const float* x   = (const float*)d_in[0];
    const int*   ei  = (const int*)  d_in[1];
    const float* t1w = (const float*)d_in[2];
    const float* t1b = (const float*)d_in[3];
    const float* gw  = (const float*)d_in[4];
    const float* gb  = (const float*)d_in[5];
    const float* w2  = (const float*)d_in[6];
    const float* b2  = (const float*)d_in[7];
    float* out = (float*)d_out;

    char* p = (char*)d_ws;
    int*    colptr   = (int*)p;    p += (size_t)(N_NODES + 64) * 4;
    int*    partials = (int*)p;    p += 256 * 4;
    float*  nd       = (float*)p;  p += (size_t)N_NODES * 4;
    int*    cnt      = (int*)p;    p += (size_t)N_NODES * 4;
    float*  dcb      = (float*)p;  p += (size_t)N_NODES * 4;
    float2* dn       = (float2*)p; p += (size_t)N_NODES * 8;
    int*    csr      = (int*)p;    p += (size_t)N_EDGES * 4;
    _Float16* wh     = (_Float16*)p; p += (size_t)HIDDEN * 512 * 2;
    // transient region (dead after k_scatter2) overlaps the h buffers:
    char* q = p;
    unsigned int*   part   = (unsigned int*)q;                 // 2*64*12500*4 = 6.4 MB
    unsigned short* cntpre = (unsigned short*)(q + (size_t)2 * NCHUNK * NWORDS * 4);   // 6.4 MB
    // h region (written from k_gemm1 onward)
    __half2* hb0 = (__half2*)p; p += (size_t)N_NODES * 64 * 4;   // 12.8 MB
    __half2* hb1 = (__half2*)p; p += (size_t)N_NODES * 64 * 4;   // 12.8 MB
    float*  h0   = (float*)p;   p += (size_t)N_NODES * HIDDEN * 4;
    float*  h1   = (float*)p;   p += (size_t)N_NODES * HIDDEN * 4;
    float*  h2   = (float*)p;   p += (size_t)N_NODES * HIDDEN * 4;

    // ---- graph preprocessing (zero global atomics) ----
    k_hist<<<128, 256, 0, stream>>>(ei, part);
    k_reduce<<<(NWORDS + 255) / 256, 256, 0, stream>>>(part, nd, cnt, cntpre);
    int nb = (N_NODES + 1023) / 1024;   // 49
    k_scan_a<<<nb, 256, 0, stream>>>(cnt, colptr, partials);
    k_scan_b<<<1, 64, 0, stream>>>(partials, colptr, nb);
    k_scan_c<<<(N_NODES + 255) / 256, 256, 0, stream>>>(colptr, partials);
    k_scatter2<<<NCHUNK, 256, 0, stream>>>(ei, colptr, cntpre, csr);

    // ---- dense pipeline ----
    k_cvt<<<(16384 + 255) / 256, 256, 0, stream>>>((const float4*)t1w, (__half2*)wh, 16384);
    k_gemm1<<<(N_NODES + 63) / 64, 256, 0, stream>>>(x, wh, t1b, h0, (_Float16*)hb0);

    k_dot <<<(N_NODES + 3) / 4, 256, 0, stream>>>(h0, gw, gb, nd, 0, dn, dcb);
    k_prop<<<(N_NODES + 3) / 4, 256, 0, stream>>>(hb0, h0, colptr, csr, dn, dcb, nd, h1, hb1);

    k_dot <<<(N_NODES + 3) / 4, 256, 0, stream>>>(h1, gw, gb, nd, 1, dn, dcb);
    k_prop<<<(N_NODES + 3) / 4, 256, 0, stream>>>(hb1, h0, colptr, csr, dn, dcb, nd, h2, hb0);

    k_out<<<(N_NODES + 3) / 4, 256, 0, stream>>>(h2, w2, b2, out);
}